// Round 12
// baseline (80451.575 us; speedup 1.0000x reference)
//
#include <hip/hip_runtime.h>

// ---- problem constants ----
constexpr int SQ = 8192;   // sequence length
constexpr int HD = 256;    // hidden size H
constexpr int NG = 1024;   // 4H (gate width)

typedef __fp16 h2 __attribute__((ext_vector_type(2)));
typedef __fp16 f16x8 __attribute__((ext_vector_type(8)));
typedef float f32x4 __attribute__((ext_vector_type(4)));
typedef unsigned int uint;
typedef unsigned short ushort;

__device__ __forceinline__ float sigm_f(float x) {
  float e = __builtin_amdgcn_exp2f(-1.4426950408889634f * x);
  return __builtin_amdgcn_rcpf(1.0f + e);
}
__device__ __forceinline__ float tanh_f(float x) {
  float e = __builtin_amdgcn_exp2f(2.885390081777927f * x);
  return 1.0f - 2.0f * __builtin_amdgcn_rcpf(1.0f + e);
}
__device__ __forceinline__ uint pk(float a, float b) {
  return __builtin_bit_cast(uint, __builtin_amdgcn_cvt_pkrtz(a, b));
}
__device__ __forceinline__ f16x8 bcf(uint4 v) { return __builtin_bit_cast(f16x8, v); }

// =====================================================================
// xp GEMM: out[d][m][n] = sum_k A[m][k] * W[d][k][n] + bias[d][n]
// =====================================================================
__global__ __launch_bounds__(256) void gemm_xp(const float* __restrict__ A, int K,
                                               const float* __restrict__ W,
                                               const float* __restrict__ bias,
                                               float* __restrict__ out) {
  __shared__ float Al[16][64];  // [k][m]
  __shared__ float Bl[16][64];  // [k][n]
  const int tid = threadIdx.x;
  const int bm = blockIdx.x * 64;
  const int d  = blockIdx.y >> 4;
  const int bn = (blockIdx.y & 15) * 64;
  const float* Wd = W + (size_t)d * K * NG;
  const float* bd = bias + (size_t)d * NG;
  float* outd = out + (size_t)d * SQ * NG;

  const int m4 = (tid >> 4) << 2;
  const int n4 = (tid & 15) << 2;
  const int am = tid >> 2, ak = (tid & 3) << 2;
  const int bk = tid >> 4, bnn = (tid & 15) << 2;

  float acc[4][4] = {};
  for (int kt = 0; kt < K; kt += 16) {
    float4 av = *(const float4*)(A + (size_t)(bm + am) * K + kt + ak);
    float4 bv = *(const float4*)(Wd + (size_t)(kt + bk) * NG + bn + bnn);
    __syncthreads();
    Al[ak + 0][am] = av.x;
    Al[ak + 1][am] = av.y;
    Al[ak + 2][am] = av.z;
    Al[ak + 3][am] = av.w;
    *(float4*)&Bl[bk][bnn] = bv;
    __syncthreads();
#pragma unroll
    for (int k = 0; k < 16; ++k) {
      float4 a = *(const float4*)&Al[k][m4];
      float4 b = *(const float4*)&Bl[k][n4];
      float ar[4] = {a.x, a.y, a.z, a.w};
      float br[4] = {b.x, b.y, b.z, b.w};
#pragma unroll
      for (int i = 0; i < 4; ++i)
#pragma unroll
        for (int jj = 0; jj < 4; ++jj)
          acc[i][jj] = fmaf(ar[i], br[jj], acc[i][jj]);
    }
  }
#pragma unroll
  for (int i = 0; i < 4; ++i) {
    float4 o;
    o.x = acc[i][0] + bd[bn + n4 + 0];
    o.y = acc[i][1] + bd[bn + n4 + 1];
    o.z = acc[i][2] + bd[bn + n4 + 2];
    o.w = acc[i][3] + bd[bn + n4 + 3];
    *(float4*)(outd + (size_t)(bm + m4 + i) * NG + bn + n4) = o;
  }
}

// =====================================================================
// LSTM recurrence v13 (MFMA): 1 WG/direction, 512 threads (8 waves).
// Wave w owns units [w*32, w*32+32). Col-group c (0..7): g=c>>1, hh=c&1,
// colbase = g*256 + w*32 + hh*16. Per step, per wave: 8 cgs x 8 kslices
// of v_mfma_f32_16x16x32_f16:
//   A (16x32) = h slice, identical in every row: lane reads the same
//     16B as its lane-group (4-addr broadcast) -> all C rows equal.
//   B (32x16) = W fragment: lane l holds W[ks*32+(l>>4)*8+2q(+1)]
//     [colbase+(l&15)] as h2 pairs. Step-invariant: cg 0..5 in 192
//     VGPRs (AGPR-native for MFMA), cg 6..7 in LDS (128KB, flat
//     conflict-free [cg6*8+ks][j]).
// Extraction: C[0] in lanes 0..15 = pre-activation for col colbase+l.
// Lane l<16 holds all 4 gates of units u0=w*32+l and u1=u0+16 ->
// local tail (no gate exchange), h written as 2 ushorts, one raw
// lgkmcnt-only s_barrier per step. LDS 129KB -> 1 block/CU.
// =====================================================================
__global__ __launch_bounds__(512, 1) void lstm_mfma(const float* __restrict__ Whh,
                                                    const float* __restrict__ xp,
                                                    float* __restrict__ obuf) {
  __shared__ uint4 wl[16 * 512];   // 128KB: [(cg6*8+ks)][j]
  __shared__ uint  hl[2][128];     // h f16-packed: dword r = (h[2r],h[2r+1])
  const int d = blockIdx.x;
  const int j = threadIdx.x;
  const int w = j >> 6;
  const int l = j & 63;
  const int col16 = l & 15;        // col within 16-tile
  const int g4 = l >> 4;           // lane quad-group (k-block)
  const float* W   = Whh + (size_t)d * HD * NG;
  const float* xpd = xp + (size_t)d * SQ * NG;

  // ---- per-cg column offsets (static after unroll) ----
  // off(c) = (c>>1)*256 + w*32 + (c&1)*16 + col16

  // ---- register B fragments: cg 0..5 ----
  f16x8 wb[6][8];
#pragma unroll
  for (int c = 0; c < 6; ++c) {
    const int colb = (c >> 1) * 256 + w * 32 + (c & 1) * 16 + col16;
#pragma unroll
    for (int ks = 0; ks < 8; ++ks) {
      const int r0 = ks * 32 + g4 * 8;
      uint4 v;
      v.x = pk(W[(size_t)(r0 + 0) * NG + colb], W[(size_t)(r0 + 1) * NG + colb]);
      v.y = pk(W[(size_t)(r0 + 2) * NG + colb], W[(size_t)(r0 + 3) * NG + colb]);
      v.z = pk(W[(size_t)(r0 + 4) * NG + colb], W[(size_t)(r0 + 5) * NG + colb]);
      v.w = pk(W[(size_t)(r0 + 6) * NG + colb], W[(size_t)(r0 + 7) * NG + colb]);
      wb[c][ks] = bcf(v);
    }
  }
  // ---- LDS B fragments: cg 6..7 ----
#pragma unroll
  for (int c6 = 0; c6 < 2; ++c6) {
    const int colb = 3 * 256 + w * 32 + c6 * 16 + col16;
#pragma unroll
    for (int ks = 0; ks < 8; ++ks) {
      const int r0 = ks * 32 + g4 * 8;
      uint4 v;
      v.x = pk(W[(size_t)(r0 + 0) * NG + colb], W[(size_t)(r0 + 1) * NG + colb]);
      v.y = pk(W[(size_t)(r0 + 2) * NG + colb], W[(size_t)(r0 + 3) * NG + colb]);
      v.z = pk(W[(size_t)(r0 + 4) * NG + colb], W[(size_t)(r0 + 5) * NG + colb]);
      v.w = pk(W[(size_t)(r0 + 6) * NG + colb], W[(size_t)(r0 + 7) * NG + colb]);
      wl[(c6 * 8 + ks) * 512 + j] = v;
    }
  }

  if (j < 256) ((uint*)hl)[j] = 0u;
  __syncthreads();

  const int fwd = (d == 0) ? 1 : 0;
  int t = fwd ? 0 : SQ - 1;
  const int dt = fwd ? 1 : -1;
  const int u0 = w * 32 + col16;
  const int u1 = u0 + 16;
  float cc0 = 0.0f, cc1 = 0.0f;
  int p = 0;

  float xc[8], xn[8] = {};
#pragma unroll
  for (int c = 0; c < 8; ++c)
    xc[c] = xpd[(size_t)t * NG + (c >> 1) * 256 + w * 32 + (c & 1) * 16 + col16];

  for (int step = 0; step < SQ; ++step) {
    // prefetch next-step xp (global; never drained by the raw barrier)
    if (step + 1 < SQ) {
#pragma unroll
      for (int c = 0; c < 8; ++c)
        xn[c] = xpd[(size_t)(t + dt) * NG + (c >> 1) * 256 + w * 32 + (c & 1) * 16 + col16];
    }

    float pre[8];
    // ---- half 0: cgs 0..3 (all register B) ----
    {
      f32x4 c0 = {0.f, 0.f, 0.f, 0.f}, c1 = c0, c2 = c0, c3 = c0;
#pragma unroll
      for (int ks = 0; ks < 8; ++ks) {
        f16x8 a = bcf(*(const uint4*)&hl[p][ks * 16 + g4 * 4]);   // broadcast
        c0 = __builtin_amdgcn_mfma_f32_16x16x32_f16(a, wb[0][ks], c0, 0, 0, 0);
        c1 = __builtin_amdgcn_mfma_f32_16x16x32_f16(a, wb[1][ks], c1, 0, 0, 0);
        c2 = __builtin_amdgcn_mfma_f32_16x16x32_f16(a, wb[2][ks], c2, 0, 0, 0);
        c3 = __builtin_amdgcn_mfma_f32_16x16x32_f16(a, wb[3][ks], c3, 0, 0, 0);
      }
      pre[0] = c0[0]; pre[1] = c1[0]; pre[2] = c2[0]; pre[3] = c3[0];
    }
    // ---- half 1: cgs 4,5 (reg) + 6,7 (LDS) ----
    {
      f32x4 c0 = {0.f, 0.f, 0.f, 0.f}, c1 = c0, c2 = c0, c3 = c0;
#pragma unroll
      for (int ks = 0; ks < 8; ++ks) {
        f16x8 a = bcf(*(const uint4*)&hl[p][ks * 16 + g4 * 4]);
        c0 = __builtin_amdgcn_mfma_f32_16x16x32_f16(a, wb[4][ks], c0, 0, 0, 0);
        c1 = __builtin_amdgcn_mfma_f32_16x16x32_f16(a, wb[5][ks], c1, 0, 0, 0);
        uint4 w6 = wl[(0 * 8 + ks) * 512 + j];
        c2 = __builtin_amdgcn_mfma_f32_16x16x32_f16(a, bcf(w6), c2, 0, 0, 0);
        uint4 w7 = wl[(1 * 8 + ks) * 512 + j];
        c3 = __builtin_amdgcn_mfma_f32_16x16x32_f16(a, bcf(w7), c3, 0, 0, 0);
      }
      pre[4] = c0[0]; pre[5] = c1[0]; pre[6] = c2[0]; pre[7] = c3[0];
    }

    // ---- tail: all lanes hold valid values for col16 (redundant x4) ----
    float i0 = sigm_f(pre[0] + xc[0]);   // c=0: gate i, unit u0
    float i1 = sigm_f(pre[1] + xc[1]);   // c=1: gate i, unit u1
    float f0 = sigm_f(pre[2] + xc[2]);   // c=2: gate f, u0
    float f1 = sigm_f(pre[3] + xc[3]);
    float g0 = tanh_f(pre[4] + xc[4]);   // c=4: gate g, u0
    float g1 = tanh_f(pre[5] + xc[5]);
    float o0 = sigm_f(pre[6] + xc[6]);   // c=6: gate o, u0
    float o1 = sigm_f(pre[7] + xc[7]);
    cc0 = f0 * cc0 + i0 * g0;
    cc1 = f1 * cc1 + i1 * g1;
    float hv0 = o0 * tanh_f(cc0);
    float hv1 = o1 * tanh_f(cc1);

    if (l < 16) {
      obuf[(size_t)t * 512 + (d << 8) + u0] = hv0;   // fire-and-forget
      obuf[(size_t)t * 512 + (d << 8) + u1] = hv1;
      ushort* hp = (ushort*)hl[p ^ 1];
      hp[u0] = (ushort)(pk(hv0, hv0) & 0xFFFFu);
      hp[u1] = (ushort)(pk(hv1, hv1) & 0xFFFFu);
    }

    // ---- one raw barrier: LDS ordering only, no vmcnt drain ----
    asm volatile("s_waitcnt lgkmcnt(0)" ::: "memory");
    __builtin_amdgcn_s_barrier();
    __builtin_amdgcn_sched_barrier(0);

    p ^= 1;
#pragma unroll
    for (int c = 0; c < 8; ++c) xc[c] = xn[c];
    t += dt;
  }
}

// =====================================================================
// classifier head
// =====================================================================
__global__ void cls_k(const float* __restrict__ buf, const float* __restrict__ w1,
                      const float* __restrict__ b1, const float* __restrict__ w2,
                      const float* __restrict__ b2, float* __restrict__ out) {
  __shared__ float feat[512];
  __shared__ float hid[32];
  const int t = threadIdx.x;
  feat[t] = (t < 256) ? buf[(size_t)(SQ - 1) * 512 + t] : buf[t];
  __syncthreads();
  if (t < 32) {
    float a = b1[t];
    for (int k = 0; k < 512; ++k) a = fmaf(feat[k], w1[k * 32 + t], a);
    hid[t] = a;
  }
  __syncthreads();
  if (t < 2) {
    float a = b2[t];
    for (int k = 0; k < 32; ++k) a = fmaf(hid[k], w2[k * 2 + t], a);
    out[t] = a;
  }
}

// =====================================================================
extern "C" void kernel_launch(void* const* d_in, const int* in_sizes, int n_in,
                              void* d_out, int out_size, void* d_ws, size_t ws_size,
                              hipStream_t stream) {
  const float* x     = (const float*)d_in[0];
  const float* w_ih0 = (const float*)d_in[1];
  const float* w_hh0 = (const float*)d_in[2];
  const float* b0    = (const float*)d_in[3];
  const float* w_ih  = (const float*)d_in[4];
  const float* w_hh  = (const float*)d_in[5];
  const float* b     = (const float*)d_in[6];
  const float* w1    = (const float*)d_in[7];
  const float* b1    = (const float*)d_in[8];
  const float* w2    = (const float*)d_in[9];
  const float* b2    = (const float*)d_in[10];

  float* xp   = (float*)d_ws;                       // [2][SQ][NG] = 64MB
  float* bufA = xp + (size_t)2 * SQ * NG;           // [SQ][512]   = 16MB
  float* bufB = bufA + (size_t)SQ * 512;            // [SQ][512]   = 16MB

  const dim3 ggrid(SQ / 64, 32);

  // layer 0
  gemm_xp<<<ggrid, 256, 0, stream>>>(x, 1024, w_ih0, b0, xp);
  lstm_mfma<<<2, 512, 0, stream>>>(w_hh0, xp, bufA);

  // layers 1..4
  float* cur = bufA;
  float* nxt = bufB;
  for (int lyr = 0; lyr < 4; ++lyr) {
    gemm_xp<<<ggrid, 256, 0, stream>>>(cur, 512, w_ih + (size_t)lyr * 2 * 512 * 1024,
                                       b + (size_t)lyr * 2 * 1024, xp);
    lstm_mfma<<<2, 512, 0, stream>>>(w_hh + (size_t)lyr * 2 * 256 * 1024, xp, nxt);
    float* tmp = cur; cur = nxt; nxt = tmp;
  }

  cls_k<<<1, 512, 0, stream>>>(cur, w1, b1, w2, b2, (float*)d_out);
}

// Round 13
// 74700.824 us; speedup vs baseline: 1.0770x; 1.0770x over previous
//
#include <hip/hip_runtime.h>

// ---- problem constants ----
constexpr int SQ = 8192;   // sequence length
constexpr int HD = 256;    // hidden size H
constexpr int NG = 1024;   // 4H (gate width)

typedef __fp16 h2 __attribute__((ext_vector_type(2)));
typedef unsigned int uint;
typedef unsigned short ushort;

__device__ __forceinline__ float sigm_f(float x) {
  float e = __builtin_amdgcn_exp2f(-1.4426950408889634f * x);
  return __builtin_amdgcn_rcpf(1.0f + e);
}
__device__ __forceinline__ float tanh_f(float x) {
  float e = __builtin_amdgcn_exp2f(2.885390081777927f * x);
  return 1.0f - 2.0f * __builtin_amdgcn_rcpf(1.0f + e);
}
__device__ __forceinline__ h2 bch2(uint v) { return __builtin_bit_cast(h2, v); }
__device__ __forceinline__ uint pk(float a, float b) {
  return __builtin_bit_cast(uint, __builtin_amdgcn_cvt_pkrtz(a, b));
}
// xor lane-bit-0 exchange via DPP quad_perm [1,0,3,2] — pure VALU
__device__ __forceinline__ float dpp_xor1(float x) {
  int v = __builtin_amdgcn_mov_dpp(__builtin_bit_cast(int, x), 0xB1, 0xF, 0xF, true);
  return __builtin_bit_cast(float, v);
}

// =====================================================================
// xp GEMM: out[d][m][n] = sum_k A[m][k] * W[d][k][n] + bias[d][n]
// =====================================================================
__global__ __launch_bounds__(256) void gemm_xp(const float* __restrict__ A, int K,
                                               const float* __restrict__ W,
                                               const float* __restrict__ bias,
                                               float* __restrict__ out) {
  __shared__ float Al[16][64];  // [k][m]
  __shared__ float Bl[16][64];  // [k][n]
  const int tid = threadIdx.x;
  const int bm = blockIdx.x * 64;
  const int d  = blockIdx.y >> 4;
  const int bn = (blockIdx.y & 15) * 64;
  const float* Wd = W + (size_t)d * K * NG;
  const float* bd = bias + (size_t)d * NG;
  float* outd = out + (size_t)d * SQ * NG;

  const int m4 = (tid >> 4) << 2;
  const int n4 = (tid & 15) << 2;
  const int am = tid >> 2, ak = (tid & 3) << 2;
  const int bk = tid >> 4, bnn = (tid & 15) << 2;

  float acc[4][4] = {};
  for (int kt = 0; kt < K; kt += 16) {
    float4 av = *(const float4*)(A + (size_t)(bm + am) * K + kt + ak);
    float4 bv = *(const float4*)(Wd + (size_t)(kt + bk) * NG + bn + bnn);
    __syncthreads();
    Al[ak + 0][am] = av.x;
    Al[ak + 1][am] = av.y;
    Al[ak + 2][am] = av.z;
    Al[ak + 3][am] = av.w;
    *(float4*)&Bl[bk][bnn] = bv;
    __syncthreads();
#pragma unroll
    for (int k = 0; k < 16; ++k) {
      float4 a = *(const float4*)&Al[k][m4];
      float4 b = *(const float4*)&Bl[k][n4];
      float ar[4] = {a.x, a.y, a.z, a.w};
      float br[4] = {b.x, b.y, b.z, b.w};
#pragma unroll
      for (int i = 0; i < 4; ++i)
#pragma unroll
        for (int jj = 0; jj < 4; ++jj)
          acc[i][jj] = fmaf(ar[i], br[jj], acc[i][jj]);
    }
  }
#pragma unroll
  for (int i = 0; i < 4; ++i) {
    float4 o;
    o.x = acc[i][0] + bd[bn + n4 + 0];
    o.y = acc[i][1] + bd[bn + n4 + 1];
    o.z = acc[i][2] + bd[bn + n4 + 2];
    o.w = acc[i][3] + bd[bn + n4 + 3];
    *(float4*)(outd + (size_t)(bm + m4 + i) * NG + bn + n4) = o;
  }
}

// =====================================================================
// LSTM recurrence v16: per-wave K-half + scalar (readlane) h operands.
// 512 threads, 8 waves. Wave w: pair = w>>1, s = w&1 (K-half).
// Thread (w,l): unit u = pair*64 + l; owns gate cols {g*256+u} over
// rows [s*128, s*128+128):
//   rows +0..95:  48 h2 x 4 gates = 192 weight VGPRs
//   rows +96..127: LDS wl[(g*4+qq)*512+j] (128KB, lane-consecutive b128)
// h delivery: ONE ds_read_b128/wave (lanes 0..15 hold the half's 64
// dwords), then __builtin_amdgcn_readlane per h2 -> wave-uniform scalar
// operand to fdot2. Replaces 16 broadcast LDS reads/wave/step with 1.
// K-combine: 16B partial float4 through LDS + barrier B1; both pair
// waves redundantly run the tail (identical FP). h written by s==0
// waves (even lanes, DPP-packed). Barrier B2 ends the step.
// Raw lgkmcnt-only barriers (no vmcnt drain). LDS ~133KB -> 1 block/CU.
// =====================================================================
__global__ __launch_bounds__(512, 1) void lstm_rec16(const float* __restrict__ Whh,
                                                     const float* __restrict__ xp,
                                                     float* __restrict__ obuf) {
  __shared__ uint4 wl[16 * 512];      // 128KB: [(g*4+qq)][j]
  __shared__ uint  hl[2][128];        // h f16-packed: dword r = (h[2r],h[2r+1])
  __shared__ float part[4][2][64][4]; // [pair][s][l][gate] partial sums, 8KB
  const int d = blockIdx.x;
  const int j = threadIdx.x;
  const int w = j >> 6;
  const int l = j & 63;
  const int pair = w >> 1;
  const int s = w & 1;                // K-half (wave-uniform)
  const int u = pair * 64 + l;        // unit 0..255
  const float* W   = Whh + (size_t)d * HD * NG;
  const float* xpd = xp + (size_t)d * SQ * NG;

  // ---- LDS weights: rows [s*128+96, s*128+128) for this thread's 4 cols ----
#pragma unroll
  for (int g = 0; g < 4; ++g) {
#pragma unroll
    for (int qq = 0; qq < 4; ++qq) {
      const int r0 = s * 128 + 96 + 8 * qq;
      const int c  = g * 256 + u;
      uint4 v;
      v.x = pk(W[(size_t)(r0 + 0) * NG + c], W[(size_t)(r0 + 1) * NG + c]);
      v.y = pk(W[(size_t)(r0 + 2) * NG + c], W[(size_t)(r0 + 3) * NG + c]);
      v.z = pk(W[(size_t)(r0 + 4) * NG + c], W[(size_t)(r0 + 5) * NG + c]);
      v.w = pk(W[(size_t)(r0 + 6) * NG + c], W[(size_t)(r0 + 7) * NG + c]);
      wl[(g * 4 + qq) * 512 + j] = v;
    }
  }

  // ---- register weights: rows [s*128, s*128+96) for 4 gate cols ----
  h2 wr[4][48];
#pragma unroll
  for (int g = 0; g < 4; ++g) {
    const float* Wc = W + (size_t)(s * 128) * NG + g * 256 + u;
#pragma unroll
    for (int k = 0; k < 48; ++k)
      wr[g][k] = __builtin_amdgcn_cvt_pkrtz(Wc[(size_t)(2 * k) * NG],
                                            Wc[(size_t)(2 * k + 1) * NG]);
  }

  if (j < 256) ((uint*)hl)[j] = 0u;
  __syncthreads();

  const int fwd = (d == 0) ? 1 : 0;
  int t = fwd ? 0 : SQ - 1;
  const int dt = fwd ? 1 : -1;
  float cc = 0.0f;
  int p = 0;

  float xc[4], xn[4] = {};
#pragma unroll
  for (int g = 0; g < 4; ++g) xc[g] = xpd[(size_t)t * NG + g * 256 + u];

  for (int step = 0; step < SQ; ++step) {
    // prefetch next xp (global; never drained by the raw barriers)
    if (step + 1 < SQ) {
#pragma unroll
      for (int g = 0; g < 4; ++g) xn[g] = xpd[(size_t)(t + dt) * NG + g * 256 + u];
    }

    // ---- fill: one b128 -> lanes 0..15 hold this half's 64 h-dwords ----
    uint4 vh = *(const uint4*)&hl[p][s * 64 + (l & 15) * 4];

    float acc0 = 0.0f, acc1 = 0.0f, acc2 = 0.0f, acc3 = 0.0f;
    // ---- register rows: k-dwords 0..47 via readlane scalar operands ----
#pragma unroll
    for (int k = 0; k < 48; ++k) {
      const int comp = k & 3, lane = k >> 2;
      uint hk;
      if      (comp == 0) hk = (uint)__builtin_amdgcn_readlane(__builtin_bit_cast(int, vh.x), lane);
      else if (comp == 1) hk = (uint)__builtin_amdgcn_readlane(__builtin_bit_cast(int, vh.y), lane);
      else if (comp == 2) hk = (uint)__builtin_amdgcn_readlane(__builtin_bit_cast(int, vh.z), lane);
      else                hk = (uint)__builtin_amdgcn_readlane(__builtin_bit_cast(int, vh.w), lane);
      h2 hh = bch2(hk);
      acc0 = __builtin_amdgcn_fdot2(wr[0][k], hh, acc0, false);
      acc1 = __builtin_amdgcn_fdot2(wr[1][k], hh, acc1, false);
      acc2 = __builtin_amdgcn_fdot2(wr[2][k], hh, acc2, false);
      acc3 = __builtin_amdgcn_fdot2(wr[3][k], hh, acc3, false);
    }
    // ---- LDS rows: k-dwords 48..63 ----
#pragma unroll
    for (int qq = 0; qq < 4; ++qq) {
      uint4 wq0 = wl[(0 * 4 + qq) * 512 + j];
      uint4 wq1 = wl[(1 * 4 + qq) * 512 + j];
      uint4 wq2 = wl[(2 * 4 + qq) * 512 + j];
      uint4 wq3 = wl[(3 * 4 + qq) * 512 + j];
#pragma unroll
      for (int kk = 0; kk < 4; ++kk) {
        const int k = 48 + qq * 4 + kk;
        const int comp = k & 3, lane = k >> 2;
        uint hk;
        if      (comp == 0) hk = (uint)__builtin_amdgcn_readlane(__builtin_bit_cast(int, vh.x), lane);
        else if (comp == 1) hk = (uint)__builtin_amdgcn_readlane(__builtin_bit_cast(int, vh.y), lane);
        else if (comp == 2) hk = (uint)__builtin_amdgcn_readlane(__builtin_bit_cast(int, vh.z), lane);
        else                hk = (uint)__builtin_amdgcn_readlane(__builtin_bit_cast(int, vh.w), lane);
        h2 hh = bch2(hk);
        const uint w0c = (kk == 0) ? wq0.x : (kk == 1) ? wq0.y : (kk == 2) ? wq0.z : wq0.w;
        const uint w1c = (kk == 0) ? wq1.x : (kk == 1) ? wq1.y : (kk == 2) ? wq1.z : wq1.w;
        const uint w2c = (kk == 0) ? wq2.x : (kk == 1) ? wq2.y : (kk == 2) ? wq2.z : wq2.w;
        const uint w3c = (kk == 0) ? wq3.x : (kk == 1) ? wq3.y : (kk == 2) ? wq3.z : wq3.w;
        acc0 = __builtin_amdgcn_fdot2(bch2(w0c), hh, acc0, false);
        acc1 = __builtin_amdgcn_fdot2(bch2(w1c), hh, acc1, false);
        acc2 = __builtin_amdgcn_fdot2(bch2(w2c), hh, acc2, false);
        acc3 = __builtin_amdgcn_fdot2(bch2(w3c), hh, acc3, false);
      }
    }

    // ---- publish partials; B1; combine with partner wave ----
    *(float4*)&part[pair][s][l][0] = make_float4(acc0, acc1, acc2, acc3);
    asm volatile("s_waitcnt lgkmcnt(0)" ::: "memory");
    __builtin_amdgcn_s_barrier();
    __builtin_amdgcn_sched_barrier(0);

    float4 po = *(const float4*)&part[pair][s ^ 1][l][0];
    float pre0 = acc0 + po.x + xc[0];
    float pre1 = acc1 + po.y + xc[1];
    float pre2 = acc2 + po.z + xc[2];
    float pre3 = acc3 + po.w + xc[3];

    // ---- redundant tail in both pair waves (identical FP) ----
    float iv = sigm_f(pre0);
    float fv = sigm_f(pre1);
    float gv = tanh_f(pre2);
    float ov = sigm_f(pre3);
    cc = fv * cc + iv * gv;
    float hv = ov * tanh_f(cc);

    if (s == 0) {                       // wave-uniform branch
      obuf[(size_t)t * 512 + (d << 8) + u] = hv;   // fire-and-forget
      float hn = dpp_xor1(hv);          // even lane gets odd partner's h
      if (!(l & 1))
        hl[p ^ 1][(u >> 1)] = pk(hv, hn);
    }

    // ---- B2: h(p^1) visible; everyone done with part/hl(p) ----
    asm volatile("s_waitcnt lgkmcnt(0)" ::: "memory");
    __builtin_amdgcn_s_barrier();
    __builtin_amdgcn_sched_barrier(0);

    p ^= 1;
#pragma unroll
    for (int g = 0; g < 4; ++g) xc[g] = xn[g];
    t += dt;
  }
}

// =====================================================================
// classifier head
// =====================================================================
__global__ void cls_k(const float* __restrict__ buf, const float* __restrict__ w1,
                      const float* __restrict__ b1, const float* __restrict__ w2,
                      const float* __restrict__ b2, float* __restrict__ out) {
  __shared__ float feat[512];
  __shared__ float hid[32];
  const int t = threadIdx.x;
  feat[t] = (t < 256) ? buf[(size_t)(SQ - 1) * 512 + t] : buf[t];
  __syncthreads();
  if (t < 32) {
    float a = b1[t];
    for (int k = 0; k < 512; ++k) a = fmaf(feat[k], w1[k * 32 + t], a);
    hid[t] = a;
  }
  __syncthreads();
  if (t < 2) {
    float a = b2[t];
    for (int k = 0; k < 32; ++k) a = fmaf(hid[k], w2[k * 2 + t], a);
    out[t] = a;
  }
}

// =====================================================================
extern "C" void kernel_launch(void* const* d_in, const int* in_sizes, int n_in,
                              void* d_out, int out_size, void* d_ws, size_t ws_size,
                              hipStream_t stream) {
  const float* x     = (const float*)d_in[0];
  const float* w_ih0 = (const float*)d_in[1];
  const float* w_hh0 = (const float*)d_in[2];
  const float* b0    = (const float*)d_in[3];
  const float* w_ih  = (const float*)d_in[4];
  const float* w_hh  = (const float*)d_in[5];
  const float* b     = (const float*)d_in[6];
  const float* w1    = (const float*)d_in[7];
  const float* b1    = (const float*)d_in[8];
  const float* w2    = (const float*)d_in[9];
  const float* b2    = (const float*)d_in[10];

  float* xp   = (float*)d_ws;                       // [2][SQ][NG] = 64MB
  float* bufA = xp + (size_t)2 * SQ * NG;           // [SQ][512]   = 16MB
  float* bufB = bufA + (size_t)SQ * 512;            // [SQ][512]   = 16MB

  const dim3 ggrid(SQ / 64, 32);

  // layer 0
  gemm_xp<<<ggrid, 256, 0, stream>>>(x, 1024, w_ih0, b0, xp);
  lstm_rec16<<<2, 512, 0, stream>>>(w_hh0, xp, bufA);

  // layers 1..4
  float* cur = bufA;
  float* nxt = bufB;
  for (int lyr = 0; lyr < 4; ++lyr) {
    gemm_xp<<<ggrid, 256, 0, stream>>>(cur, 512, w_ih + (size_t)lyr * 2 * 512 * 1024,
                                       b + (size_t)lyr * 2 * 1024, xp);
    lstm_rec16<<<2, 512, 0, stream>>>(w_hh + (size_t)lyr * 2 * 256 * 1024, xp, nxt);
    float* tmp = cur; cur = nxt; nxt = tmp;
  }

  cls_k<<<1, 512, 0, stream>>>(cur, w1, b1, w2, b2, (float*)d_out);
}